// Round 19
// baseline (222.074 us; speedup 1.0000x reference)
//
#include <hip/hip_runtime.h>

// Problem constants (match reference)
#define NB 32
#define CH 3
#define HH 768
#define WW 768

// Producer-consumer wave specialization on the R12 geometry:
// 320 threads = 4 consumer waves (conv) + 1 producer wave (stage next tile).
// Double-buffered LDS, ONE barrier per tile; stage overlaps conv fully.
#define TW 64
#define TH 16
#define SW 72                   // staged width: [tw0-4, tw0+68)
#define SWP 76                  // LDS row stride
#define SH (TH + 4)             // 20 staged rows
#define CSTRIDE (SH * SWP)
#define TPB 8                   // tiles per chain (128 rows)
#define NTC (WW / TW)           // 12
#define NTG (HH / (TH * TPB))   // 6
#define NWG (NB * NTC * NTG)    // 2304, %8==0
#define UNITS (SH * (SW / 4))   // 360 float4-units per tile
#define NTHR 320                // 256 consumers + 64 producer

typedef float v4f __attribute__((ext_vector_type(4)));  // NT stores

// Pair-swap swizzle (R11): logical in-row float f at physical
// f ^ (((f>>5)&1)<<1); granules 8..15 store halves swapped. Conv b64 reads
// then cover all 32 banks exactly once across the 16 tx lanes.
__device__ inline int pswz(int s) { return s ^ (((s >> 5) & 1) << 1); }

__global__ __launch_bounds__(NTHR) void colwarp_conv_kernel(
    const float* __restrict__ im,
    const float* __restrict__ flat,
    float* __restrict__ out)
{
    // XCD-contiguous mapping (R12): one XCD owns whole images (4 each).
    const int d   = blockIdx.x;
    const int wid = (d & 7) * (NWG / 8) + (d >> 3);
    const int tc  = wid % NTC;
    const int t2  = wid / NTC;
    const int tg  = t2 % NTG;
    const int b   = t2 / NTG;
    const int tw0 = tc * TW;
    const int thbase = tg * (TPB * TH);

    __shared__ float xs[2][CH][SH][SWP];   // 36480 B -> 4 blocks/CU (20 waves)

    const int tid = threadIdx.x;
    const bool producer = (tid >= 256);

    // ---- per-sample params (block-uniform -> scalar) ----
    const float* f = flat + b * 37;
    float Wm[3][3];
#pragma unroll
    for (int i = 0; i < 3; ++i)
#pragma unroll
        for (int j = 0; j < 3; ++j) Wm[i][j] = f[i * 3 + j];
    float sh3[3];
#pragma unroll
    for (int i = 0; i < 3; ++i) sh3[i] = f[9 + i];
    float K[5][5];
#pragma unroll
    for (int i = 0; i < 5; ++i)
#pragma unroll
        for (int j = 0; j < 5; ++j) K[i][j] = f[12 + i * 5 + j];
    float bias[3];
#pragma unroll
    for (int c = 0; c < 3; ++c)
        bias[c] = sh3[0]*Wm[0][c] + sh3[1]*Wm[1][c] + sh3[2]*Wm[2][c];

    const size_t plane = (size_t)HH * WW;
    const float* im0 = im + (size_t)b * CH * plane;

    // ---- producer unit descriptors: u = plane-lane + 64*ui, ui 0..5 ----
    const int pl = tid - 256;              // producer lane (garbage for consumers; unused)
    int pur[6], puldso[6], pugw[6];
    bool puon[6], puswap[6];
#pragma unroll
    for (int ui = 0; ui < 6; ++ui) {
        const int u  = (pl < 0 ? 0 : pl) + 64 * ui;
        const int rr = u / (SW / 4);
        const int c4 = u - rr * (SW / 4);  // granule 0..17
        pur[ui]    = rr;
        puldso[ui] = rr * SWP + c4 * 4;
        pugw[ui]   = tw0 - 4 + c4 * 4;
        puon[ui]   = (u < UNITS);
        puswap[ui] = ((c4 >> 3) & 1) != 0;
    }

    float4 pv[3][CH];   // one batch (3 units) in flight
    bool pok[3];

    // Load batch BASE..BASE+2 for tile at row TH0.
#define P_LOAD(BASE, TH0)                                                      \
    _Pragma("unroll")                                                          \
    for (int k = 0; k < 3; ++k) {                                              \
        const int ui = (BASE) + k;                                             \
        const int gh = (TH0) + pur[ui] - 2;                                    \
        const bool ok = puon[ui] && ((unsigned)gh < (unsigned)HH)              \
                                 && ((unsigned)pugw[ui] < (unsigned)WW);       \
        pok[k] = ok;                                                           \
        if (ok) {                                                              \
            const size_t off = (size_t)gh * WW + pugw[ui];                     \
            pv[k][0] = *(const float4*)(im0 + off);                            \
            pv[k][1] = *(const float4*)(im0 + plane + off);                    \
            pv[k][2] = *(const float4*)(im0 + 2 * plane + off);                \
        }                                                                      \
    }

    // Mix + swizzled write of batch BASE..BASE+2 into BUFP.
#define P_WRITE(BASE, BUFP)                                                    \
    _Pragma("unroll")                                                          \
    for (int k = 0; k < 3; ++k) {                                              \
        const int ui = (BASE) + k;                                             \
        if (puon[ui]) {                                                        \
            float4 m0 = make_float4(0.f, 0.f, 0.f, 0.f), m1 = m0, m2 = m0;     \
            if (pok[k]) {                                                      \
                const float4 a0 = pv[k][0], a1 = pv[k][1], a2 = pv[k][2];      \
                m0.x = a0.x*Wm[0][0] + a1.x*Wm[1][0] + a2.x*Wm[2][0] + bias[0];\
                m0.y = a0.y*Wm[0][0] + a1.y*Wm[1][0] + a2.y*Wm[2][0] + bias[0];\
                m0.z = a0.z*Wm[0][0] + a1.z*Wm[1][0] + a2.z*Wm[2][0] + bias[0];\
                m0.w = a0.w*Wm[0][0] + a1.w*Wm[1][0] + a2.w*Wm[2][0] + bias[0];\
                m1.x = a0.x*Wm[0][1] + a1.x*Wm[1][1] + a2.x*Wm[2][1] + bias[1];\
                m1.y = a0.y*Wm[0][1] + a1.y*Wm[1][1] + a2.y*Wm[2][1] + bias[1];\
                m1.z = a0.z*Wm[0][1] + a1.z*Wm[1][1] + a2.z*Wm[2][1] + bias[1];\
                m1.w = a0.w*Wm[0][1] + a1.w*Wm[1][1] + a2.w*Wm[2][1] + bias[1];\
                m2.x = a0.x*Wm[0][2] + a1.x*Wm[1][2] + a2.x*Wm[2][2] + bias[2];\
                m2.y = a0.y*Wm[0][2] + a1.y*Wm[1][2] + a2.y*Wm[2][2] + bias[2];\
                m2.z = a0.z*Wm[0][2] + a1.z*Wm[1][2] + a2.z*Wm[2][2] + bias[2];\
                m2.w = a0.w*Wm[0][2] + a1.w*Wm[1][2] + a2.w*Wm[2][2] + bias[2];\
            }                                                                  \
            const bool sw = puswap[ui];                                        \
            const float4 w0 = sw ? make_float4(m0.z,m0.w,m0.x,m0.y) : m0;      \
            const float4 w1 = sw ? make_float4(m1.z,m1.w,m1.x,m1.y) : m1;      \
            const float4 w2 = sw ? make_float4(m2.z,m2.w,m2.x,m2.y) : m2;      \
            *(float4*)((BUFP) + 0 * CSTRIDE + puldso[ui]) = w0;                \
            *(float4*)((BUFP) + 1 * CSTRIDE + puldso[ui]) = w1;               \
            *(float4*)((BUFP) + 2 * CSTRIDE + puldso[ui]) = w2;                \
        }                                                                      \
    }

#define P_STAGE(BUFP, TH0)                                                     \
    { P_LOAD(0, TH0); P_WRITE(0, BUFP); P_LOAD(3, TH0); P_WRITE(3, BUFP); }

    // ---- consumer mapping (tid < 256): identical to R12 ----
    const int tx = tid & 15;
    const int ty = (tid >> 4) & 15;
    const int r0 = ty;

    const int offA = pswz(4 * tx + 2);
    const int offB = pswz(4 * tx + 4);
    const int offC = pswz(4 * tx + 6);
    const int offD = pswz(4 * tx + 8);

#define CONV_STORE(BUFP, TH0)                                                  \
    {                                                                          \
        float acc[CH][4];                                                      \
        _Pragma("unroll")                                                      \
        for (int c = 0; c < CH; ++c)                                           \
            _Pragma("unroll")                                                  \
            for (int o = 0; o < 4; ++o) acc[c][o] = 0.f;                       \
        _Pragma("unroll")                                                      \
        for (int rr = 0; rr < 5; ++rr) {                                       \
            _Pragma("unroll")                                                  \
            for (int c = 0; c < CH; ++c) {                                     \
                const float* rowb = (BUFP) + c * CSTRIDE + (r0 + rr) * SWP;    \
                const float2 p0 = *(const float2*)(rowb + offA);               \
                const float2 p1 = *(const float2*)(rowb + offB);               \
                const float2 p2 = *(const float2*)(rowb + offC);               \
                const float2 p3 = *(const float2*)(rowb + offD);               \
                const float w8[8] = {p0.x, p0.y, p1.x, p1.y,                   \
                                     p2.x, p2.y, p3.x, p3.y};                  \
                _Pragma("unroll")                                              \
                for (int j = 0; j < 5; ++j) {                                  \
                    _Pragma("unroll")                                          \
                    for (int o = 0; o < 4; ++o)                                \
                        acc[c][o] += w8[o + j] * K[rr][j];                     \
                }                                                              \
            }                                                                  \
        }                                                                      \
        _Pragma("unroll")                                                      \
        for (int c = 0; c < CH; ++c) {                                         \
            float* ob = out + ((size_t)b * CH + c) * plane;                    \
            v4f vv = {acc[c][0], acc[c][1], acc[c][2], acc[c][3]};             \
            __builtin_nontemporal_store(vv,                                    \
                (v4f*)&ob[(size_t)((TH0) + r0) * WW + tw0 + tx * 4]);          \
        }                                                                      \
    }

    // ---- prologue: producer stages tile 0 into buf 0 ----
    if (producer) { P_STAGE(&xs[0][0][0][0], thbase); }
    __syncthreads();

    // ---- steady state: ONE barrier per tile ----
#pragma unroll 1
    for (int t = 0; t < TPB; ++t) {
        const int th0 = thbase + t * TH;
        if (producer) {
            if (t + 1 < TPB) { P_STAGE(&xs[(t & 1) ^ 1][0][0][0], th0 + TH); }
        } else {
            CONV_STORE(&xs[t & 1][0][0][0], th0);
        }
        __syncthreads();   // producer done writing buf[t+1], consumers done buf[t]
    }
}

extern "C" void kernel_launch(void* const* d_in, const int* in_sizes, int n_in,
                              void* d_out, int out_size, void* d_ws, size_t ws_size,
                              hipStream_t stream) {
    const float* im   = (const float*)d_in[0];
    const float* flat = (const float*)d_in[1];
    float* out        = (float*)d_out;

    colwarp_conv_kernel<<<dim3(NWG), dim3(NTHR), 0, stream>>>(im, flat, out);
}

// Round 20
// 88.135 us; speedup vs baseline: 2.5197x; 2.5197x over previous
//
#include <hip/hip_runtime.h>

// Problem constants (match reference)
#define NB 32
#define CH 3
#define HH 768
#define WW 768

// R12 pipeline at TW=128 with RY=2:
//  - DS read bytes/output: 120 -> 72 B (heaviest non-HBM pipe, -40%)
//  - halo fraction 1.125 -> 1.06
//  - NWG=1152 at 4-blocks/CU capacity (1024) -> 1.125 launch rounds (R12's
//    tail ratio; R13's RY=2 test was confounded by 2.25 rounds)
#define TW 128
#define TH 16
#define SW 136                  // staged width: [tw0-4, tw0+132)
#define SWP 140                 // LDS row stride (140%32=12; 560B row, 16B-aligned)
#define SH (TH + 4)             // 20 staged rows
#define CSTRIDE (SH * SWP)
#define TPB 8                   // tiles per chain (128 rows)
#define NTC (WW / TW)           // 6
#define NTG (HH / (TH * TPB))   // 6
#define NWG (NB * NTC * NTG)    // 1152, %8==0
#define GRAN (SW / 4)           // 34 granules per row
#define UNITS (SH * GRAN)       // 680 float4-units per tile
#define RY 2

typedef float v4f __attribute__((ext_vector_type(4)));  // NT stores

// Pair-swap swizzle (R11): logical in-row float f at physical
// f ^ (((f>>5)&1)<<1). At 32-lane tx the residual alias is 2-way (free).
__device__ inline int pswz(int s) { return s ^ (((s >> 5) & 1) << 1); }

__global__ __launch_bounds__(256) void colwarp_conv_kernel(
    const float* __restrict__ im,
    const float* __restrict__ flat,
    float* __restrict__ out)
{
    // XCD-contiguous mapping: each XCD owns 144 consecutive wids = 4 images.
    const int d   = blockIdx.x;
    const int wid = (d & 7) * (NWG / 8) + (d >> 3);
    const int tc  = wid % NTC;
    const int t2  = wid / NTC;
    const int tg  = t2 % NTG;
    const int b   = t2 / NTG;
    const int tw0 = tc * TW;
    const int thbase = tg * (TPB * TH);

    // SINGLE buffer: 3*20*140*4 = 33600 B -> 4 blocks/CU (16 waves)
    __shared__ float xs[CH][SH][SWP];

    const int tid = threadIdx.x;

    // ---- per-sample params (b block-uniform -> scalar) ----
    const float* f = flat + b * 37;
    float Wm[3][3];
#pragma unroll
    for (int i = 0; i < 3; ++i)
#pragma unroll
        for (int j = 0; j < 3; ++j) Wm[i][j] = f[i * 3 + j];
    float sh3[3];
#pragma unroll
    for (int i = 0; i < 3; ++i) sh3[i] = f[9 + i];
    float K[5][5];
#pragma unroll
    for (int i = 0; i < 5; ++i)
#pragma unroll
        for (int j = 0; j < 5; ++j) K[i][j] = f[12 + i * 5 + j];
    float bias[3];
#pragma unroll
    for (int c = 0; c < 3; ++c)
        bias[c] = sh3[0]*Wm[0][c] + sh3[1]*Wm[1][c] + sh3[2]*Wm[2][c];

    const size_t plane = (size_t)HH * WW;
    const float* im0 = im + (size_t)b * CH * plane;

    // ---- staging units: u = tid + 256*ui, ui 0..2 (680 total) ----
    int ur[3], uldso[3], ugw[3];
    bool uon[3], uswap[3];
#pragma unroll
    for (int ui = 0; ui < 3; ++ui) {
        const int u  = tid + 256 * ui;
        const int rr = u / GRAN;
        const int g  = u - rr * GRAN;         // granule 0..33
        ur[ui]    = rr;
        uldso[ui] = rr * SWP + g * 4;         // linear granule address
        ugw[ui]   = tw0 - 4 + g * 4;
        uon[ui]   = (u < UNITS);
        uswap[ui] = ((g >> 3) & 1) != 0;      // float bit5 per granule
    }

    float4 vld[3][CH];   // in-flight raw loads (36 floats)
    bool vok[3];

#define STAGE_LOAD(TH0)                                                        \
    _Pragma("unroll")                                                          \
    for (int ui = 0; ui < 3; ++ui) {                                           \
        const int gh = (TH0) + ur[ui] - 2;                                     \
        const bool ok = uon[ui] && ((unsigned)gh < (unsigned)HH)               \
                                && ((unsigned)ugw[ui] < (unsigned)WW);         \
        vok[ui] = ok;                                                          \
        if (ok) {                                                              \
            const size_t off = (size_t)gh * WW + ugw[ui];                      \
            vld[ui][0] = *(const float4*)(im0 + off);                          \
            vld[ui][1] = *(const float4*)(im0 + plane + off);                  \
            vld[ui][2] = *(const float4*)(im0 + 2 * plane + off);              \
        }                                                                      \
    }

#define STAGE_WRITE(BUFP)                                                      \
    _Pragma("unroll")                                                          \
    for (int ui = 0; ui < 3; ++ui) {                                           \
        if (uon[ui]) {                                                         \
            float4 m0 = make_float4(0.f, 0.f, 0.f, 0.f), m1 = m0, m2 = m0;     \
            if (vok[ui]) {                                                     \
                const float4 a0 = vld[ui][0], a1 = vld[ui][1], a2 = vld[ui][2];\
                m0.x = a0.x*Wm[0][0] + a1.x*Wm[1][0] + a2.x*Wm[2][0] + bias[0];\
                m0.y = a0.y*Wm[0][0] + a1.y*Wm[1][0] + a2.y*Wm[2][0] + bias[0];\
                m0.z = a0.z*Wm[0][0] + a1.z*Wm[1][0] + a2.z*Wm[2][0] + bias[0];\
                m0.w = a0.w*Wm[0][0] + a1.w*Wm[1][0] + a2.w*Wm[2][0] + bias[0];\
                m1.x = a0.x*Wm[0][1] + a1.x*Wm[1][1] + a2.x*Wm[2][1] + bias[1];\
                m1.y = a0.y*Wm[0][1] + a1.y*Wm[1][1] + a2.y*Wm[2][1] + bias[1];\
                m1.z = a0.z*Wm[0][1] + a1.z*Wm[1][1] + a2.z*Wm[2][1] + bias[1];\
                m1.w = a0.w*Wm[0][1] + a1.w*Wm[1][1] + a2.w*Wm[2][1] + bias[1];\
                m2.x = a0.x*Wm[0][2] + a1.x*Wm[1][2] + a2.x*Wm[2][2] + bias[2];\
                m2.y = a0.y*Wm[0][2] + a1.y*Wm[1][2] + a2.y*Wm[2][2] + bias[2];\
                m2.z = a0.z*Wm[0][2] + a1.z*Wm[1][2] + a2.z*Wm[2][2] + bias[2];\
                m2.w = a0.w*Wm[0][2] + a1.w*Wm[1][2] + a2.w*Wm[2][2] + bias[2];\
            }                                                                  \
            const bool sw = uswap[ui];                                         \
            const float4 w0 = sw ? make_float4(m0.z,m0.w,m0.x,m0.y) : m0;      \
            const float4 w1 = sw ? make_float4(m1.z,m1.w,m1.x,m1.y) : m1;      \
            const float4 w2 = sw ? make_float4(m2.z,m2.w,m2.x,m2.y) : m2;      \
            *(float4*)((BUFP) + 0 * CSTRIDE + uldso[ui]) = w0;                 \
            *(float4*)((BUFP) + 1 * CSTRIDE + uldso[ui]) = w1;                 \
            *(float4*)((BUFP) + 2 * CSTRIDE + uldso[ui]) = w2;                 \
        }                                                                      \
    }

    const int tx = tid & 31;      // 4 output cols (32 tx groups)
    const int ty = tid >> 5;      // 0..7, 2 output rows each
    const int r0 = ty * RY;

    // Window logical floats 4tx+2..4tx+9 as 4 float2 pairs (pair-swizzled):
    const int offA = pswz(4 * tx + 2);
    const int offB = pswz(4 * tx + 4);
    const int offC = pswz(4 * tx + 6);
    const int offD = pswz(4 * tx + 8);

#define CONV_STORE(BUFP, TH0)                                                  \
    {                                                                          \
        float acc[CH][RY][4];                                                  \
        _Pragma("unroll")                                                      \
        for (int c = 0; c < CH; ++c)                                           \
            _Pragma("unroll")                                                  \
            for (int r = 0; r < RY; ++r)                                       \
                _Pragma("unroll")                                              \
                for (int o = 0; o < 4; ++o) acc[c][r][o] = 0.f;                \
        _Pragma("unroll")                                                      \
        for (int rr = 0; rr < RY + 4; ++rr) {                                  \
            _Pragma("unroll")                                                  \
            for (int c = 0; c < CH; ++c) {                                     \
                const float* rowb = (BUFP) + c * CSTRIDE + (r0 + rr) * SWP;    \
                const float2 p0 = *(const float2*)(rowb + offA);               \
                const float2 p1 = *(const float2*)(rowb + offB);               \
                const float2 p2 = *(const float2*)(rowb + offC);               \
                const float2 p3 = *(const float2*)(rowb + offD);               \
                const float w8[8] = {p0.x, p0.y, p1.x, p1.y,                   \
                                     p2.x, p2.y, p3.x, p3.y};                  \
                _Pragma("unroll")                                              \
                for (int i = 0; i < 5; ++i) {                                  \
                    const int r = rr - i;                                      \
                    if (r >= 0 && r < RY) {                                    \
                        _Pragma("unroll")                                      \
                        for (int j = 0; j < 5; ++j) {                          \
                            _Pragma("unroll")                                  \
                            for (int o = 0; o < 4; ++o)                        \
                                acc[c][r][o] += w8[o + j] * K[i][j];           \
                        }                                                      \
                    }                                                          \
                }                                                              \
            }                                                                  \
        }                                                                      \
        _Pragma("unroll")                                                      \
        for (int c = 0; c < CH; ++c) {                                         \
            float* ob = out + ((size_t)b * CH + c) * plane;                    \
            _Pragma("unroll")                                                  \
            for (int r = 0; r < RY; ++r) {                                     \
                v4f vv = {acc[c][r][0], acc[c][r][1],                          \
                          acc[c][r][2], acc[c][r][3]};                         \
                __builtin_nontemporal_store(vv,                                \
                    (v4f*)&ob[(size_t)((TH0) + r0 + r) * WW + tw0 + tx * 4]);  \
            }                                                                  \
        }                                                                      \
    }

    // ---- prologue: stage tile 0 ----
    STAGE_LOAD(thbase);
    STAGE_WRITE(&xs[0][0][0]);
    __syncthreads();

    // ---- chained single-buffer pipeline: load-early, write-late ----
#pragma unroll 1
    for (int t = 0; t < TPB; ++t) {
        const int th0 = thbase + t * TH;
        if (t + 1 < TPB) { STAGE_LOAD(th0 + TH); }   // HBM issue hides under conv
        CONV_STORE(&xs[0][0][0], th0);
        __syncthreads();                              // all reads of buffer done
        if (t + 1 < TPB) {
            STAGE_WRITE(&xs[0][0][0]);                // mix + write next tile
            __syncthreads();                          // buffer ready
        }
    }
}

extern "C" void kernel_launch(void* const* d_in, const int* in_sizes, int n_in,
                              void* d_out, int out_size, void* d_ws, size_t ws_size,
                              hipStream_t stream) {
    const float* im   = (const float*)d_in[0];
    const float* flat = (const float*)d_in[1];
    float* out        = (float*)d_out;

    colwarp_conv_kernel<<<dim3(NWG), dim3(256), 0, stream>>>(im, flat, out);
}